// Round 7
// baseline (120.931 us; speedup 1.0000x reference)
//
#include <hip/hip_runtime.h>
#include <math.h>

#define N_A   1024
#define HDIM  128
#define DIN   172
#define E_CNT 256
#define LP    72      // LDS pitch in bf16 elems

typedef __attribute__((ext_vector_type(8))) short bf16x8;
typedef __attribute__((ext_vector_type(4))) float f32x4;

__device__ __forceinline__ unsigned short f2bf(float x) {
    unsigned int u = __float_as_uint(x);
    unsigned int r = (u + 0x7fffu + ((u >> 16) & 1u)) >> 16;
    return (unsigned short)r;
}

// Gauss-Legendre nodes/weights mapped to [0,1] (tau=1)
__constant__ float c_t[8] = {
    0.4082826787521751f, 0.2372337950418355f, 0.10166676129318665f, 0.019855071751231843f,
    0.5917173212478249f, 0.7627662049581645f, 0.8983332387068134f, 0.9801449282487682f};
__constant__ float c_w[8] = {
    0.181341891689181f, 0.15685332293894365f, 0.11119051722668725f, 0.05061426814518815f,
    0.181341891689181f, 0.15685332293894365f, 0.11119051722668725f, 0.05061426814518815f};

// ---------------------------------------------------------------------------
// fp32 -> bf16 for L and dL (A operands, K-contiguous)
// ---------------------------------------------------------------------------
__global__ __launch_bounds__(256)
void conv_bf16(const float* __restrict__ L, const float* __restrict__ dL,
               unsigned short* __restrict__ Lb, unsigned short* __restrict__ dLb)
{
    const int t = blockIdx.x * 256 + threadIdx.x;      // 524288 threads, 4 elems each
    const float* src = (t < 262144) ? L : dL;
    unsigned short* dst = (t < 262144) ? Lb : dLb;
    const int q = (t < 262144) ? t : t - 262144;
    float4 v = *(const float4*)(src + (size_t)q * 4);
    ushort4 o;
    o.x = f2bf(v.x); o.y = f2bf(v.y); o.z = f2bf(v.z); o.w = f2bf(v.w);
    *(ushort4*)(dst + (size_t)q * 4) = o;
}

// ---------------------------------------------------------------------------
// wave-based 128-wide row reduction (2 waves per block)
// ---------------------------------------------------------------------------
__device__ __forceinline__ float rowsum128(float v, float* red2, int j)
{
    #pragma unroll
    for (int o = 32; o > 0; o >>= 1) v += __shfl_xor(v, o, 64);
    if ((j & 63) == 0) red2[j >> 6] = v;
    __syncthreads();
    const float t = red2[0] + red2[1];
    __syncthreads();
    return t;
}

// ---------------------------------------------------------------------------
// per-row "pre" body: rmsnorm -> delta -> Bz -> V,U ; writes VU/VUt/dlt
// ---------------------------------------------------------------------------
__device__ __forceinline__ void pre_body(
    float x, int i, int j,
    const float* __restrict__ rms_scale, const float* __restrict__ W_B,
    const float* __restrict__ b_B, const float* __restrict__ W_dt,
    const float* __restrict__ b_dt, const float* __restrict__ A_log,
    const float* __restrict__ m_vec, const int* __restrict__ act_ids,
    float* __restrict__ VU, unsigned short* __restrict__ VUt,
    float* __restrict__ dlt, float* xs, float* red2)
{
    const float ss = rowsum128(x * x, red2, j);
    const float rms = sqrtf(ss) * 0.08838834764831845f;   // /sqrt(128)
    const float xn = rms_scale[j] * x / (rms + 1e-8f);
    xs[j] = xn;
    const float dsum = rowsum128(xn * W_dt[j], red2, j);  // includes barrier for xs
    const float dd = dsum + b_dt[0];
    const float delta = dd > 0.f ? dd + log1pf(expf(-dd)) : log1pf(expf(dd));

    float acc = b_B[j];
    #pragma unroll 8
    for (int k = 0; k < HDIM; ++k) acc += xs[k] * W_B[k * HDIM + j];

    const float V = acc * delta;
    const int aid = act_ids[i];
    const float U = m_vec[(size_t)aid * HDIM + j] * expf(-delta * expf(A_log[j]));

    VU[(size_t)i * 256 + j] = V;
    VU[(size_t)i * 256 + 128 + j] = U;
    VUt[(size_t)j * 1024 + i] = f2bf(V);
    VUt[(size_t)(128 + j) * 1024 + i] = f2bf(U);
    if (j == 0) dlt[i] = delta;
}

// ---------------------------------------------------------------------------
// ew_head: zt = [x_sub|neigh]@W_tune + b_tune, then pre(stage 1)
// ---------------------------------------------------------------------------
__global__ __launch_bounds__(128)
void ew_head(const float* __restrict__ x_sub, const float* __restrict__ names,
             const int* __restrict__ src, const int* __restrict__ dst,
             const float* __restrict__ W_tune, const float* __restrict__ b_tune,
             const float* __restrict__ rms1, const float* __restrict__ W_B1,
             const float* __restrict__ b_B1, const float* __restrict__ W_dt,
             const float* __restrict__ b_dt, const float* __restrict__ A1,
             const float* __restrict__ m1, const int* __restrict__ act,
             float* __restrict__ zt, float* __restrict__ VU,
             unsigned short* __restrict__ VUt, float* __restrict__ dlt1)
{
    const int i = blockIdx.x, j = threadIdx.x;
    __shared__ float xl[DIN + 2];
    __shared__ float xs[HDIM];
    __shared__ float red2[2];

    for (int k = j; k < DIN; k += 128) xl[k] = x_sub[(size_t)i * DIN + k];
    if (j == 0) {
        float n0 = 0.f, n1 = 0.f;
        if (i < E_CNT)            { n0 = names[src[i]];          n1 = names[dst[i]]; }
        else if (i < 2 * E_CNT)   { n0 = names[dst[i - E_CNT]];  n1 = names[src[i - E_CNT]]; }
        xl[DIN] = n0; xl[DIN + 1] = n1;
    }
    __syncthreads();
    float acc = b_tune[j];
    #pragma unroll 2
    for (int k = 0; k < DIN + 2; ++k) acc += xl[k] * W_tune[k * HDIM + j];
    zt[(size_t)i * HDIM + j] = acc;

    pre_body(acc, i, j, rms1, W_B1, b_B1, W_dt, b_dt, A1, m1, act,
             VU, VUt, dlt1, xs, red2);
}

// ---------------------------------------------------------------------------
// GA: per slot (blockIdx.x): 0,1 -> type G (LV tile, cols slot*64 of V)
//                            2,3 -> type T (LU and dLU tiles, cols of U)
// epilogue: G = V - 0.1 LV -> GTt rows 0:128 (bf16 ^T) + Gf fp32
//           T = U - 0.1 LU - 0.05 dLU -> GTt rows 128:256
// ---------------------------------------------------------------------------
__global__ __launch_bounds__(256)
void gemm_ga(const unsigned short* __restrict__ Lb, const unsigned short* __restrict__ dLb,
             const unsigned short* __restrict__ VUt, const float* __restrict__ VU,
             unsigned short* __restrict__ GTt, float* __restrict__ Gf)
{
    const int slot = blockIdx.x, rb = blockIdx.y;
    const bool typeT = slot >= 2;
    const int cb = typeT ? slot - 2 : slot;
    const int bn0 = (typeT ? 128 : 0) + cb * 64;

    __shared__ unsigned short AsL[64 * LP];
    __shared__ unsigned short AsD[64 * LP];
    __shared__ unsigned short Bs[64 * LP];

    const int tid = threadIdx.x;
    const int srow = tid >> 2, skc = (tid & 3) << 4;

    const unsigned short* aL = Lb  + (size_t)(rb * 64 + srow) * 1024 + skc;
    const unsigned short* aD = dLb + (size_t)(rb * 64 + srow) * 1024 + skc;
    const unsigned short* bg = VUt + (size_t)(bn0 + srow) * 1024 + skc;

    const int lane = tid & 63, w = tid >> 6;
    const int wrow = (w >> 1) * 32, wcol = (w & 1) * 32;
    const int fr = lane & 15, fg = lane >> 4, fk = fg << 3;

    f32x4 acc[2][2] = {};
    f32x4 acc2[2][2] = {};

    bf16x8 pa0 = *(const bf16x8*)aL, pa1 = *(const bf16x8*)(aL + 8);
    bf16x8 pb0 = *(const bf16x8*)bg, pb1 = *(const bf16x8*)(bg + 8);
    bf16x8 pd0 = {}, pd1 = {};
    if (typeT) { pd0 = *(const bf16x8*)aD; pd1 = *(const bf16x8*)(aD + 8); }

    for (int k0 = 0; k0 < 1024; k0 += 64) {
        __syncthreads();
        *(bf16x8*)&AsL[srow * LP + skc] = pa0; *(bf16x8*)&AsL[srow * LP + skc + 8] = pa1;
        *(bf16x8*)&Bs[srow * LP + skc]  = pb0; *(bf16x8*)&Bs[srow * LP + skc + 8]  = pb1;
        if (typeT) { *(bf16x8*)&AsD[srow * LP + skc] = pd0; *(bf16x8*)&AsD[srow * LP + skc + 8] = pd1; }
        __syncthreads();
        if (k0 + 64 < 1024) {
            pa0 = *(const bf16x8*)(aL + k0 + 64); pa1 = *(const bf16x8*)(aL + k0 + 72);
            pb0 = *(const bf16x8*)(bg + k0 + 64); pb1 = *(const bf16x8*)(bg + k0 + 72);
            if (typeT) { pd0 = *(const bf16x8*)(aD + k0 + 64); pd1 = *(const bf16x8*)(aD + k0 + 72); }
        }
        #pragma unroll
        for (int h = 0; h < 2; ++h) {
            const int ko = h * 32 + fk;
            bf16x8 a0 = *(const bf16x8*)&AsL[(wrow + fr) * LP + ko];
            bf16x8 a1 = *(const bf16x8*)&AsL[(wrow + 16 + fr) * LP + ko];
            bf16x8 b0 = *(const bf16x8*)&Bs[(wcol + fr) * LP + ko];
            bf16x8 b1 = *(const bf16x8*)&Bs[(wcol + 16 + fr) * LP + ko];
            acc[0][0] = __builtin_amdgcn_mfma_f32_16x16x32_bf16(a0, b0, acc[0][0], 0, 0, 0);
            acc[0][1] = __builtin_amdgcn_mfma_f32_16x16x32_bf16(a0, b1, acc[0][1], 0, 0, 0);
            acc[1][0] = __builtin_amdgcn_mfma_f32_16x16x32_bf16(a1, b0, acc[1][0], 0, 0, 0);
            acc[1][1] = __builtin_amdgcn_mfma_f32_16x16x32_bf16(a1, b1, acc[1][1], 0, 0, 0);
            if (typeT) {
                bf16x8 d0 = *(const bf16x8*)&AsD[(wrow + fr) * LP + ko];
                bf16x8 d1 = *(const bf16x8*)&AsD[(wrow + 16 + fr) * LP + ko];
                acc2[0][0] = __builtin_amdgcn_mfma_f32_16x16x32_bf16(d0, b0, acc2[0][0], 0, 0, 0);
                acc2[0][1] = __builtin_amdgcn_mfma_f32_16x16x32_bf16(d0, b1, acc2[0][1], 0, 0, 0);
                acc2[1][0] = __builtin_amdgcn_mfma_f32_16x16x32_bf16(d1, b0, acc2[1][0], 0, 0, 0);
                acc2[1][1] = __builtin_amdgcn_mfma_f32_16x16x32_bf16(d1, b1, acc2[1][1], 0, 0, 0);
            }
        }
    }

    #pragma unroll
    for (int m = 0; m < 2; ++m) {
        const int gm = rb * 64 + wrow + m * 16 + fg * 4;
        #pragma unroll
        for (int n = 0; n < 2; ++n) {
            const int gj = cb * 64 + wcol + n * 16 + fr;   // 0..127
            float gv[4];
            #pragma unroll
            for (int r = 0; r < 4; ++r) {
                if (!typeT)
                    gv[r] = VU[(size_t)(gm + r) * 256 + gj] - 0.1f * acc[m][n][r];
                else
                    gv[r] = VU[(size_t)(gm + r) * 256 + 128 + gj]
                          - 0.1f * acc[m][n][r] - 0.05f * acc2[m][n][r];
            }
            ushort4 tv; tv.x = f2bf(gv[0]); tv.y = f2bf(gv[1]); tv.z = f2bf(gv[2]); tv.w = f2bf(gv[3]);
            *(ushort4*)&GTt[(size_t)((typeT ? 128 : 0) + gj) * 1024 + gm] = tv;
            if (!typeT) {
                #pragma unroll
                for (int r = 0; r < 4; ++r) Gf[(size_t)(gm + r) * 128 + gj] = gv[r];
            }
        }
    }
}

// ---------------------------------------------------------------------------
// single-A 64x64 MFMA core
// ---------------------------------------------------------------------------
__device__ __forceinline__ void core_sa(
    const unsigned short* __restrict__ ag, const unsigned short* __restrict__ bg,
    unsigned short* As, unsigned short* Bs, int klen,
    int srow, int skc, int wrow, int wcol, int fr, int fk, f32x4 (&acc)[2][2])
{
    bf16x8 pa0 = *(const bf16x8*)ag, pa1 = *(const bf16x8*)(ag + 8);
    bf16x8 pb0 = *(const bf16x8*)bg, pb1 = *(const bf16x8*)(bg + 8);
    for (int k0 = 0; k0 < klen; k0 += 64) {
        __syncthreads();
        *(bf16x8*)&As[srow * LP + skc] = pa0; *(bf16x8*)&As[srow * LP + skc + 8] = pa1;
        *(bf16x8*)&Bs[srow * LP + skc] = pb0; *(bf16x8*)&Bs[srow * LP + skc + 8] = pb1;
        __syncthreads();
        if (k0 + 64 < klen) {
            pa0 = *(const bf16x8*)(ag + k0 + 64); pa1 = *(const bf16x8*)(ag + k0 + 72);
            pb0 = *(const bf16x8*)(bg + k0 + 64); pb1 = *(const bf16x8*)(bg + k0 + 72);
        }
        #pragma unroll
        for (int h = 0; h < 2; ++h) {
            const int ko = h * 32 + fk;
            bf16x8 a0 = *(const bf16x8*)&As[(wrow + fr) * LP + ko];
            bf16x8 a1 = *(const bf16x8*)&As[(wrow + 16 + fr) * LP + ko];
            bf16x8 b0 = *(const bf16x8*)&Bs[(wcol + fr) * LP + ko];
            bf16x8 b1 = *(const bf16x8*)&Bs[(wcol + 16 + fr) * LP + ko];
            acc[0][0] = __builtin_amdgcn_mfma_f32_16x16x32_bf16(a0, b0, acc[0][0], 0, 0, 0);
            acc[0][1] = __builtin_amdgcn_mfma_f32_16x16x32_bf16(a0, b1, acc[0][1], 0, 0, 0);
            acc[1][0] = __builtin_amdgcn_mfma_f32_16x16x32_bf16(a1, b0, acc[1][0], 0, 0, 0);
            acc[1][1] = __builtin_amdgcn_mfma_f32_16x16x32_bf16(a1, b1, acc[1][1], 0, 0, 0);
        }
    }
}

// ---------------------------------------------------------------------------
// GB: slots 0,1: H = L@G   -> HY1t rows 0:128 (bf16 ^T)
//     slots 2,3: Y1 = dL@G -> HY1t rows 128:256 + Y1f fp32
//     slots 4,5: S = dL@T  -> Sf fp32
// ---------------------------------------------------------------------------
__global__ __launch_bounds__(256)
void gemm_gb(const unsigned short* __restrict__ Lb, const unsigned short* __restrict__ dLb,
             const unsigned short* __restrict__ GTt,
             unsigned short* __restrict__ HY1t, float* __restrict__ Y1f,
             float* __restrict__ Sf)
{
    const int slot = blockIdx.x, rb = blockIdx.y;
    const unsigned short* A = (slot < 2) ? Lb : dLb;
    const int jbase = ((slot < 2) ? slot : (slot < 4) ? slot - 2 : slot - 4) * 64;
    const int bn0 = (slot < 4) ? jbase : 128 + jbase;

    __shared__ unsigned short As[64 * LP];
    __shared__ unsigned short Bs[64 * LP];

    const int tid = threadIdx.x;
    const int srow = tid >> 2, skc = (tid & 3) << 4;
    const unsigned short* ag = A   + (size_t)(rb * 64 + srow) * 1024 + skc;
    const unsigned short* bg = GTt + (size_t)(bn0 + srow) * 1024 + skc;

    const int lane = tid & 63, w = tid >> 6;
    const int wrow = (w >> 1) * 32, wcol = (w & 1) * 32;
    const int fr = lane & 15, fg = lane >> 4, fk = fg << 3;

    f32x4 acc[2][2] = {};
    core_sa(ag, bg, As, Bs, 1024, srow, skc, wrow, wcol, fr, fk, acc);

    #pragma unroll
    for (int m = 0; m < 2; ++m) {
        const int gm = rb * 64 + wrow + m * 16 + fg * 4;
        #pragma unroll
        for (int n = 0; n < 2; ++n) {
            const int gj = jbase + wcol + n * 16 + fr;
            if (slot < 4) {
                ushort4 tv;
                tv.x = f2bf(acc[m][n][0]); tv.y = f2bf(acc[m][n][1]);
                tv.z = f2bf(acc[m][n][2]); tv.w = f2bf(acc[m][n][3]);
                *(ushort4*)&HY1t[(size_t)((slot < 2 ? 0 : 128) + gj) * 1024 + gm] = tv;
                if (slot >= 2) {
                    #pragma unroll
                    for (int r = 0; r < 4; ++r) Y1f[(size_t)(gm + r) * 128 + gj] = acc[m][n][r];
                }
            } else {
                #pragma unroll
                for (int r = 0; r < 4; ++r) Sf[(size_t)(gm + r) * 128 + gj] = acc[m][n][r];
            }
        }
    }
}

// ---------------------------------------------------------------------------
// GC: dL @ [H|Y1]  (N=256), split-K S=2 -> Part fp32 partials [s][1024][256]
// ---------------------------------------------------------------------------
__global__ __launch_bounds__(256)
void gemm_gc(const unsigned short* __restrict__ dLb, const unsigned short* __restrict__ HY1t,
             float* __restrict__ Part)
{
    const int cb = blockIdx.x, rb = blockIdx.y, sz = blockIdx.z;
    const int kbase = sz * 512;

    __shared__ unsigned short As[64 * LP];
    __shared__ unsigned short Bs[64 * LP];

    const int tid = threadIdx.x;
    const int srow = tid >> 2, skc = (tid & 3) << 4;
    const unsigned short* ag = dLb  + (size_t)(rb * 64 + srow) * 1024 + kbase + skc;
    const unsigned short* bg = HY1t + (size_t)(cb * 64 + srow) * 1024 + kbase + skc;

    const int lane = tid & 63, w = tid >> 6;
    const int wrow = (w >> 1) * 32, wcol = (w & 1) * 32;
    const int fr = lane & 15, fg = lane >> 4, fk = fg << 3;

    f32x4 acc[2][2] = {};
    core_sa(ag, bg, As, Bs, 512, srow, skc, wrow, wcol, fr, fk, acc);

    float* Cb = Part + (size_t)sz * 262144;
    #pragma unroll
    for (int m = 0; m < 2; ++m) {
        const int gm = rb * 64 + wrow + m * 16 + fg * 4;
        #pragma unroll
        for (int n = 0; n < 2; ++n) {
            const int gn = cb * 64 + wcol + n * 16 + fr;
            #pragma unroll
            for (int r = 0; r < 4; ++r) Cb[(size_t)(gm + r) * 256 + gn] = acc[m][n][r];
        }
    }
}

// ---------------------------------------------------------------------------
// post body: out = U - 0.1 S + sum_k w_k (G + t(-0.1 Y1 + 0.01 Y2) + 0.005 t^2 Y3) e^{dA t}
// ---------------------------------------------------------------------------
__device__ __forceinline__ float post_body(
    int i, int j, const float* __restrict__ Part, const float* __restrict__ Gf,
    const float* __restrict__ Y1f, const float* __restrict__ Sf,
    const float* __restrict__ VU, const float* __restrict__ dlt,
    const float* __restrict__ A_log)
{
    const float y2 = Part[(size_t)i * 256 + j] + Part[262144 + (size_t)i * 256 + j];
    const float y3 = Part[(size_t)i * 256 + 128 + j] + Part[262144 + (size_t)i * 256 + 128 + j];
    const float y1 = Y1f[(size_t)i * 128 + j];
    const float s  = Sf[(size_t)i * 128 + j];
    const float g  = Gf[(size_t)i * 128 + j];
    const float u  = VU[(size_t)i * 256 + 128 + j];
    const float dA = -dlt[i] * expf(A_log[j]);
    const float bl = -0.1f * y1 + 0.01f * y2;
    const float cq = 0.005f * y3;
    float integ = 0.f;
    #pragma unroll
    for (int k = 0; k < 8; ++k) {
        const float t = c_t[k];
        integ += c_w[k] * (g + t * bl + t * t * cq) * expf(dA * t);
    }
    return u - 0.1f * s + integ;
}

// ---------------------------------------------------------------------------
// ew_mid: post(stage1) -> out[0] ; then pre(stage2) from zt + gelu(out1)
// ---------------------------------------------------------------------------
__global__ __launch_bounds__(128)
void ew_mid(const float* __restrict__ Part, const float* __restrict__ Gf,
            const float* __restrict__ Y1f, const float* __restrict__ Sf,
            const float* __restrict__ zt, const float* __restrict__ dlt1,
            const float* __restrict__ A1,
            const float* __restrict__ rms2, const float* __restrict__ W_B2,
            const float* __restrict__ b_B2, const float* __restrict__ W_dt,
            const float* __restrict__ b_dt, const float* __restrict__ A2,
            const float* __restrict__ m2, const int* __restrict__ act,
            float* __restrict__ VU, unsigned short* __restrict__ VUt,
            float* __restrict__ dlt2, float* __restrict__ out)
{
    const int i = blockIdx.x, j = threadIdx.x;
    __shared__ float xs[HDIM];
    __shared__ float red2[2];

    const float o1 = post_body(i, j, Part, Gf, Y1f, Sf, VU, dlt1, A1);
    out[(size_t)i * 128 + j] = o1;

    const float g3 = o1 * o1 * o1;
    const float gel = 0.5f * o1 * (1.0f + tanhf(0.7978845608028654f * (o1 + 0.044715f * g3)));
    const float x = zt[(size_t)i * 128 + j] + gel;

    pre_body(x, i, j, rms2, W_B2, b_B2, W_dt, b_dt, A2, m2, act,
             VU, VUt, dlt2, xs, red2);
}

// ---------------------------------------------------------------------------
// ew_tail: post(stage2) -> out[1]
// ---------------------------------------------------------------------------
__global__ __launch_bounds__(128)
void ew_tail(const float* __restrict__ Part, const float* __restrict__ Gf,
             const float* __restrict__ Y1f, const float* __restrict__ Sf,
             const float* __restrict__ VU, const float* __restrict__ dlt2,
             const float* __restrict__ A2, float* __restrict__ out)
{
    const int i = blockIdx.x, j = threadIdx.x;
    out[(size_t)i * 128 + j] = post_body(i, j, Part, Gf, Y1f, Sf, VU, dlt2, A2);
}

// ---------------------------------------------------------------------------
extern "C" void kernel_launch(void* const* d_in, const int* in_sizes, int n_in,
                              void* d_out, int out_size, void* d_ws, size_t ws_size,
                              hipStream_t stream)
{
    const float* L      = (const float*)d_in[0];
    const float* dL     = (const float*)d_in[1];
    const float* x_sub  = (const float*)d_in[2];
    const float* m1     = (const float*)d_in[3];
    const float* m2     = (const float*)d_in[4];
    const float* names  = (const float*)d_in[5];
    const float* rms1   = (const float*)d_in[6];
    const float* rms2   = (const float*)d_in[7];
    const float* W_tune = (const float*)d_in[8];
    const float* b_tune = (const float*)d_in[9];
    const float* W_B1   = (const float*)d_in[10];
    const float* b_B1   = (const float*)d_in[11];
    const float* W_B2   = (const float*)d_in[12];
    const float* b_B2   = (const float*)d_in[13];
    const float* W_dt   = (const float*)d_in[14];
    const float* b_dt   = (const float*)d_in[15];
    const float* A1     = (const float*)d_in[16];
    const float* A2     = (const float*)d_in[17];
    const int*   src    = (const int*)d_in[18];
    const int*   dst    = (const int*)d_in[19];
    const int*   act    = (const int*)d_in[20];
    float* out = (float*)d_out;

    // Workspace (~10.5 MB)
    float* ws   = (float*)d_ws;
    float* zt   = ws;                    // 131072
    float* VU   = zt   + 131072;         // 262144  fp32 [V|U]
    float* Gf   = VU   + 262144;         // 131072
    float* Y1f  = Gf   + 131072;         // 131072
    float* Sf   = Y1f  + 131072;         // 131072
    float* dlt1 = Sf   + 131072;         // 1024
    float* dlt2 = dlt1 + 1024;           // 1024
    float* Part = dlt2 + 1024;           // 524288 (GC partials, S=2)
    unsigned short* Lb    = (unsigned short*)(Part + 524288);   // 1048576
    unsigned short* dLb   = Lb    + 1048576;                    // 1048576
    unsigned short* VUt   = dLb   + 1048576;                    // 262144 [V|U]^T
    unsigned short* GTt   = VUt   + 262144;                     // 262144 [G|T]^T
    unsigned short* HY1t  = GTt   + 262144;                     // 262144 [H|Y1]^T

    conv_bf16<<<dim3(2048), dim3(256), 0, stream>>>(L, dL, Lb, dLb);

    ew_head<<<dim3(1024), dim3(128), 0, stream>>>(
        x_sub, names, src, dst, W_tune, b_tune,
        rms1, W_B1, b_B1, W_dt, b_dt, A1, m1, act,
        zt, VU, VUt, dlt1);

    // ---- stage 1 GEMM chain ----
    gemm_ga<<<dim3(4, 16), dim3(256), 0, stream>>>(Lb, dLb, VUt, VU, GTt, Gf);
    gemm_gb<<<dim3(6, 16), dim3(256), 0, stream>>>(Lb, dLb, GTt, HY1t, Y1f, Sf);
    gemm_gc<<<dim3(4, 16, 2), dim3(256), 0, stream>>>(dLb, HY1t, Part);

    ew_mid<<<dim3(1024), dim3(128), 0, stream>>>(
        Part, Gf, Y1f, Sf, zt, dlt1, A1,
        rms2, W_B2, b_B2, W_dt, b_dt, A2, m2, act,
        VU, VUt, dlt2, out);

    // ---- stage 2 GEMM chain ----
    gemm_ga<<<dim3(4, 16), dim3(256), 0, stream>>>(Lb, dLb, VUt, VU, GTt, Gf);
    gemm_gb<<<dim3(6, 16), dim3(256), 0, stream>>>(Lb, dLb, GTt, HY1t, Y1f, Sf);
    gemm_gc<<<dim3(4, 16, 2), dim3(256), 0, stream>>>(dLb, HY1t, Part);

    ew_tail<<<dim3(1024), dim3(128), 0, stream>>>(
        Part, Gf, Y1f, Sf, VU, dlt2, A2, out + 131072);
}